// Round 8
// baseline (213.185 us; speedup 1.0000x reference)
//
#include <hip/hip_runtime.h>

// GraphSAGE 2-layer + link predictor.
// CSR via 2-level bucket sort -> xcast -> gather<0> (xa) -> fused_gemm (h1 in LDS, gr out)
// -> gather<1> (h2) -> linkpred.
// Gather v4: 32 edges (8 quads) in flight per wave, masked-FMA single path.
// fused_gemm v2: 128 nodes/block, w2 overwrites w1 LDS between phases -> 2 blocks/CU.

typedef __attribute__((ext_vector_type(8))) short bf16x8;
typedef __attribute__((ext_vector_type(4))) float f32x4;

#define NBLK_A 256   // blocks in edge-chunk passes

__device__ __forceinline__ unsigned short f2bf(float f) {
    unsigned u = __float_as_uint(f);
    u = u + 0x7fffu + ((u >> 16) & 1u);   // RTNE
    return (unsigned short)(u >> 16);
}
__device__ __forceinline__ float b2f(unsigned short s) {
    return __uint_as_float(((unsigned)s) << 16);
}
__device__ __forceinline__ float uflo(unsigned v) { return __uint_as_float(v << 16); }
__device__ __forceinline__ float ufhi(unsigned v) { return __uint_as_float(v & 0xffff0000u); }

__device__ __forceinline__ long load_idx(const void* p, long i, int is64) {
    if (is64) return (long)((const long long*)p)[i];
    return (long)((const int*)p)[i];
}

__global__ void detect64_kernel(const void* eidx, int* flag) {
    const unsigned* u = (const unsigned*)eidx;
    unsigned acc = 0;
    for (int i = 0; i < 128; ++i) acc |= u[2 * i + 1];
    *flag = (acc == 0u) ? 1 : 0;
}

// Pass A: per-block LDS histogram of dst>>8. blk_hist is bucket-major [NBK][NBLK_A].
__global__ void bucket_count_kernel(const void* eidx, const int* flag,
                                    int* __restrict__ blk_hist, long E, int NBK, int chunk) {
    __shared__ int h[512];          // NBK <= 512 (N <= 131072)
    int tid = threadIdx.x, b = blockIdx.x;
    for (int i = tid; i < NBK; i += 256) h[i] = 0;
    __syncthreads();
    int is64 = *flag;
    long e0 = (long)b * chunk;
    long e1 = e0 + chunk; if (e1 > E) e1 = E;
    for (long e = e0 + tid; e < e1; e += 256) {
        long dst = load_idx(eidx, E + e, is64);
        atomicAdd(&h[(int)(dst >> 8)], 1);
    }
    __syncthreads();
    for (int i = tid; i < NBK; i += 256) blk_hist[i * NBLK_A + b] = h[i];
}

// Pass B1: total[k] = sum_b blk_hist[k][b]
__global__ void bucket_total_kernel(const int* __restrict__ blk_hist, int* __restrict__ total) {
    __shared__ int ts[256];
    int k = blockIdx.x, t = threadIdx.x;
    ts[t] = blk_hist[k * NBLK_A + t];
    __syncthreads();
    for (int off = 128; off > 0; off >>= 1) {
        if (t < off) ts[t] += ts[t + off];
        __syncthreads();
    }
    if (t == 0) total[k] = ts[0];
}

// Pass B2: exclusive scan of bucket totals; also row_start[N] = E.
__global__ void bucket_base_kernel(const int* __restrict__ total, int* __restrict__ base,
                                   int* __restrict__ row_start, int NBK, long N, long E) {
    int acc = 0;
    for (int k = 0; k < NBK; ++k) { base[k] = acc; acc += total[k]; }
    base[NBK] = acc;
    row_start[N] = (int)E;
}

// Pass B3: blk_hist[k][b] <- base[k] + exclusive_scan_b(blk_hist[k][:])
__global__ void bucket_off_kernel(int* __restrict__ blk_hist, const int* __restrict__ base) {
    __shared__ int ts[256];
    int k = blockIdx.x, t = threadIdx.x;
    int v = blk_hist[k * NBLK_A + t];
    ts[t] = v; __syncthreads();
    for (int off = 1; off < 256; off <<= 1) {
        int u = (t >= off) ? ts[t - off] : 0;
        __syncthreads();
        ts[t] += u;
        __syncthreads();
    }
    blk_hist[k * NBLK_A + t] = base[k] + ts[t] - v;
}

// Pass C: scatter packed (dst_local<<24 | src) into bucket-contiguous regions.
__global__ void bucket_scatter_kernel(const void* eidx, const int* flag,
                                      const int* __restrict__ blk_hist,
                                      unsigned* __restrict__ ebuf, long E, int NBK, int chunk) {
    __shared__ int cur[512];
    int tid = threadIdx.x, b = blockIdx.x;
    for (int i = tid; i < NBK; i += 256) cur[i] = blk_hist[i * NBLK_A + b];
    __syncthreads();
    int is64 = *flag;
    long e0 = (long)b * chunk;
    long e1 = e0 + chunk; if (e1 > E) e1 = E;
    for (long e = e0 + tid; e < e1; e += 256) {
        long src = load_idx(eidx, e, is64);
        long dst = load_idx(eidx, E + e, is64);
        int pos = atomicAdd(&cur[(int)(dst >> 8)], 1);
        ebuf[pos] = (unsigned)src | ((unsigned)(dst & 255) << 24);  // src < 2^24
    }
}

// Pass D: per-bucket counting sort in LDS -> coalesced row_start + L2-local csr writes.
__global__ void bucket_csr_kernel(const unsigned* __restrict__ ebuf, const int* __restrict__ base,
                                  int* __restrict__ csr_src, int* __restrict__ row_start, long N) {
    __shared__ int cnt[256], sc[256], cur[256];
    int k = blockIdx.x, t = threadIdx.x;
    int bstart = base[k], bend = base[k + 1];
    cnt[t] = 0;
    __syncthreads();
    for (int i = bstart + t; i < bend; i += 256)
        atomicAdd(&cnt[ebuf[i] >> 24], 1);
    __syncthreads();
    int c = cnt[t];
    sc[t] = c; __syncthreads();
    for (int off = 1; off < 256; off <<= 1) {
        int u = (t >= off) ? sc[t - off] : 0;
        __syncthreads();
        sc[t] += u;
        __syncthreads();
    }
    int loff = sc[t] - c;
    cur[t] = loff;
    long n = (long)k * 256 + t;
    if (n < N) row_start[n] = bstart + loff;
    __syncthreads();
    for (int i = bstart + t; i < bend; i += 256) {
        unsigned v = ebuf[i];
        int dl = (int)(v >> 24);
        int p = atomicAdd(&cur[dl], 1);
        csr_src[bstart + p] = (int)(v & 0xFFFFFFu);
    }
}

// x (f32) -> xa[n][64+f] (bf16). One thread per 4 floats.
__global__ void xcast_kernel(const float* __restrict__ x, unsigned short* __restrict__ xa, long N) {
    long t = (long)blockIdx.x * 256 + threadIdx.x;
    long n = t >> 4;
    int q = (int)(t & 15);
    if (n >= N) return;
    float4 v = *(const float4*)&x[n * 64 + q * 4];
    uint2 u;
    u.x = (unsigned)f2bf(v.x) | ((unsigned)f2bf(v.y) << 16);
    u.y = (unsigned)f2bf(v.z) | ((unsigned)f2bf(v.w) << 16);
    *(uint2*)&xa[n * 128 + 64 + q * 4] = u;
}

// ---------------- gather v4 ----------------
// One wave per node. Lane l: row-group lg=l>>4, feature quad fq=l&15.
// 32 edges (8 quads) per batch, all loads in flight before accumulate; masked FMA.
// MODE 0: xa[n][0:64] = mean_nbr xa[src][64:128]
// MODE 1: h2[n][0:64] = mean_nbr gr[src][0:64] + gr[n][64:128]
template <int MODE>
__global__ void gather_kernel(const int* __restrict__ rs, const int* __restrict__ csr,
                              const unsigned short* __restrict__ T,
                              unsigned short* __restrict__ Out, long N) {
    long gid = (long)blockIdx.x * 512 + threadIdx.x;
    long n = gid >> 6;
    if (n >= N) return;
    int lane = (int)(gid & 63);
    int lg = lane >> 4;
    int fq = lane & 15;
    int s = rs[n], e = rs[n + 1];
    unsigned self0 = 0, self1 = 0;
    if (MODE == 1) {                       // issue self-row load early
        uint2 sv = *(const uint2*)&T[n * 128 + 64 + fq * 4];
        self0 = sv.x; self1 = sv.y;
    }
    const int OFF = (MODE == 0) ? 64 : 0;
    const unsigned short* Tb = T + OFF + fq * 4;
    float a0 = 0.f, a1 = 0.f, a2 = 0.f, a3 = 0.f;
    for (int j = s; j < e; j += 32) {
        int idx[8]; float m[8];
#pragma unroll
        for (int d = 0; d < 8; ++d) {
            int pos = j + 4 * d + lg;
            int ok = pos < e;
            idx[d] = csr[ok ? pos : s];    // clamped: s valid whenever loop runs
            m[d] = ok ? 1.f : 0.f;
        }
        uint2 r[8];
#pragma unroll
        for (int d = 0; d < 8; ++d)
            r[d] = *(const uint2*)&Tb[(long)idx[d] * 128];
#pragma unroll
        for (int d = 0; d < 8; ++d) {
            a0 = fmaf(m[d], uflo(r[d].x), a0);
            a1 = fmaf(m[d], ufhi(r[d].x), a1);
            a2 = fmaf(m[d], uflo(r[d].y), a2);
            a3 = fmaf(m[d], ufhi(r[d].y), a3);
        }
    }
    // fold the 4 row-groups
    a0 += __shfl_xor(a0, 16, 64);  a1 += __shfl_xor(a1, 16, 64);
    a2 += __shfl_xor(a2, 16, 64);  a3 += __shfl_xor(a3, 16, 64);
    a0 += __shfl_xor(a0, 32, 64);  a1 += __shfl_xor(a1, 32, 64);
    a2 += __shfl_xor(a2, 32, 64);  a3 += __shfl_xor(a3, 32, 64);
    if (lg == 0) {
        float inv = 1.0f / fmaxf((float)(e - s), 1.0f);
        a0 *= inv; a1 *= inv; a2 *= inv; a3 *= inv;
        if (MODE == 1) {
            a0 += b2f((unsigned short)(self0 & 0xffff));
            a1 += b2f((unsigned short)(self0 >> 16));
            a2 += b2f((unsigned short)(self1 & 0xffff));
            a3 += b2f((unsigned short)(self1 >> 16));
        }
        uint2 o;
        o.x = (unsigned)f2bf(a0) | ((unsigned)f2bf(a1) << 16);
        o.y = (unsigned)f2bf(a2) | ((unsigned)f2bf(a3) << 16);
        if (MODE == 0) *(uint2*)&Out[n * 128 + fq * 4] = o;
        else           *(uint2*)&Out[n * 64 + fq * 4] = o;
    }
}

// ---------------- fused MFMA GEMM v2: gr = layer2(relu(layer1(xa))) ----------------
// W1'[o][k] = k<64 ? W1l[o][k] : W1r[o][k-64]    (128x128)
// W2'[o][k] = o<64 ? W2l[o][k] : W2r[o-64][k]    (128x128)
// 512 thr = 8 waves x 16 nodes = 128 nodes/block. wbuf holds w1 then w2 (2 barriers).
// LDS = 32(wbuf) + 32(h1t) + 1 KB -> 2 blocks/CU.
__global__ __launch_bounds__(512) void fused_gemm_kernel(
        const unsigned short* __restrict__ A,
        const float* __restrict__ W1l, const float* __restrict__ W1r, const float* __restrict__ b1,
        const float* __restrict__ W2l, const float* __restrict__ W2r, const float* __restrict__ b2,
        unsigned short* __restrict__ gr, long N) {
    __shared__ unsigned short wbuf[128 * 128];      // 32 KB, w1 then w2
    __shared__ unsigned short h1t[8][16 * 128];     // 32 KB, per-wave h1 tile
    __shared__ float bs1[128], bs2[128];
    int tid = threadIdx.x;

    // stage W1' (k-concat of W1l|W1r, each 128x64)
    for (int i = tid; i < 16384; i += 512) {
        int o = i >> 7, k = i & 127;
        float f = (k < 64) ? W1l[o * 64 + k] : W1r[o * 64 + (k - 64)];
        wbuf[(o * 128 + k) ^ ((o & 7) << 3)] = f2bf(f);
    }
    if (tid < 128) {
        bs1[tid] = b1[tid];
        bs2[tid] = (tid < 64) ? 0.f : b2[tid - 64];
    }
    __syncthreads();

    int lane = tid & 63, wid = tid >> 6;
    int l16 = lane & 15, lg = lane >> 4;
    long n0 = (long)blockIdx.x * 128 + wid * 16;
    const unsigned short* A0 = A + (n0 + l16) * 128;
    unsigned short* hw = h1t[wid];

    f32x4 acc[8];
#pragma unroll
    for (int ot = 0; ot < 8; ++ot) acc[ot] = (f32x4){0.f, 0.f, 0.f, 0.f};

    // ---- phase 1: h1 = relu(xa @ W1'.T + b1) ----
#pragma unroll
    for (int ks = 0; ks < 4; ++ks) {
        int k0 = ks * 32;
        bf16x8 a = *(const bf16x8*)&A0[k0 + 8 * lg];
#pragma unroll
        for (int ot = 0; ot < 8; ++ot) {
            int o = ot * 16 + l16;
            bf16x8 b = *(const bf16x8*)&wbuf[(o * 128 + k0 + 8 * lg) ^ ((o & 7) << 3)];
            acc[ot] = __builtin_amdgcn_mfma_f32_16x16x32_bf16(a, b, acc[ot], 0, 0, 0);
        }
    }
    // epilogue 1 -> own-wave LDS tile (row = node-local, col = o), swizzled
#pragma unroll
    for (int j = 0; j < 4; ++j) {
        int row = lg * 4 + j;
#pragma unroll
        for (int ot = 0; ot < 8; ++ot) {
            int col = ot * 16 + l16;
            float v = fmaxf(acc[ot][j] + bs1[col], 0.f);
            hw[(row * 128 + col) ^ ((row & 7) << 3)] = f2bf(v);
        }
    }
    __syncthreads();   // all w1 reads done
    // stage W2' (o-concat of W2l;W2r, each 64x128)
    for (int i = tid; i < 16384; i += 512) {
        int o = i >> 7, k = i & 127;
        float f = (o < 64) ? W2l[o * 128 + k] : W2r[(o - 64) * 128 + k];
        wbuf[(o * 128 + k) ^ ((o & 7) << 3)] = f2bf(f);
    }
    __syncthreads();

    // ---- phase 2: gr = h1 @ W2'.T + b2' ----
#pragma unroll
    for (int ot = 0; ot < 8; ++ot) acc[ot] = (f32x4){0.f, 0.f, 0.f, 0.f};
#pragma unroll
    for (int ks = 0; ks < 4; ++ks) {
        int k0 = ks * 32;
        bf16x8 a = *(const bf16x8*)&hw[(l16 * 128 + k0 + 8 * lg) ^ ((l16 & 7) << 3)];
#pragma unroll
        for (int ot = 0; ot < 8; ++ot) {
            int o = ot * 16 + l16;
            bf16x8 b = *(const bf16x8*)&wbuf[(o * 128 + k0 + 8 * lg) ^ ((o & 7) << 3)];
            acc[ot] = __builtin_amdgcn_mfma_f32_16x16x32_bf16(a, b, acc[ot], 0, 0, 0);
        }
    }
    float bval[8];
#pragma unroll
    for (int ot = 0; ot < 8; ++ot) bval[ot] = bs2[ot * 16 + l16];
#pragma unroll
    for (int j = 0; j < 4; ++j) {
        long n = n0 + lg * 4 + j;
        if (n >= N) continue;
#pragma unroll
        for (int ot = 0; ot < 8; ++ot)
            gr[n * 128 + ot * 16 + l16] = f2bf(acc[ot][j] + bval[ot]);
    }
}

// linkpred: 32 lanes per pair (16 per endpoint row), shfl reduce.
__global__ void linkpred_kernel(const void* pairs, const int* flag,
                                const unsigned short* __restrict__ h2,
                                const float* __restrict__ Wlp,
                                const float* __restrict__ blp,
                                float* __restrict__ out, long P) {
    long gid = (long)blockIdx.x * 512 + threadIdx.x;
    long p = gid >> 5;
    if (p >= P) return;
    int l32 = (int)(gid & 31);
    int half = l32 >> 4;     // 0: src emb, 1: dst emb
    int fq = l32 & 15;
    int is64 = *flag;
    long node = load_idx(pairs, 2 * p + half, is64);
    uint2 r = *(const uint2*)&h2[node * 64 + fq * 4];
    float4 wv = *(const float4*)&Wlp[half * 64 + fq * 4];
    float acc = uflo(r.x) * wv.x + ufhi(r.x) * wv.y + uflo(r.y) * wv.z + ufhi(r.y) * wv.w;
    acc += __shfl_xor(acc, 1, 64);
    acc += __shfl_xor(acc, 2, 64);
    acc += __shfl_xor(acc, 4, 64);
    acc += __shfl_xor(acc, 8, 64);
    acc += __shfl_xor(acc, 16, 64);
    if (l32 == 0) out[p] = 1.0f / (1.0f + expf(-(acc + blp[0])));
}

extern "C" void kernel_launch(void* const* d_in, const int* in_sizes, int n_in,
                              void* d_out, int out_size, void* d_ws, size_t ws_size,
                              hipStream_t stream) {
    const float* x    = (const float*)d_in[0];
    const void*  eidx  = d_in[1];
    const void*  pairs = d_in[2];
    const float* W1l = (const float*)d_in[3];
    const float* W1r = (const float*)d_in[4];
    const float* b1  = (const float*)d_in[5];
    const float* W2l = (const float*)d_in[6];
    const float* W2r = (const float*)d_in[7];
    const float* b2  = (const float*)d_in[8];
    const float* Wlp = (const float*)d_in[9];
    const float* blp = (const float*)d_in[10];
    float* out = (float*)d_out;

    long N = in_sizes[0] / 64;
    long E = in_sizes[1] / 2;
    long P = in_sizes[2] / 2;
    long N_PAD = (N + 255) & ~255L;
    int NBK = (int)((N + 255) >> 8);          // <= 512
    int chunk = (int)((E + NBLK_A - 1) / NBLK_A);

    char* w = (char*)d_ws;
    auto alloc = [&](size_t bytes) {
        char* p = w;
        w += (bytes + 255) & ~(size_t)255;
        return p;
    };
    int* row_start = (int*)alloc((N + 1) * sizeof(int));
    int* csr_src   = (int*)alloc(E * sizeof(int));
    int* blk_hist  = (int*)alloc((size_t)NBK * NBLK_A * sizeof(int));
    int* total     = (int*)alloc(NBK * sizeof(int));
    int* base      = (int*)alloc((NBK + 1) * sizeof(int));
    int* flag      = (int*)alloc(64);
    unsigned* ebuf = (unsigned*)alloc(E * sizeof(unsigned));
    unsigned short* xa = (unsigned short*)alloc((size_t)N_PAD * 128 * 2);
    unsigned short* gr = (unsigned short*)alloc((size_t)N_PAD * 128 * 2);
    unsigned short* h2 = (unsigned short*)alloc((size_t)N * 64 * 2);

    detect64_kernel<<<1, 1, 0, stream>>>(eidx, flag);

    bucket_count_kernel<<<NBLK_A, 256, 0, stream>>>(eidx, flag, blk_hist, E, NBK, chunk);
    bucket_total_kernel<<<NBK, 256, 0, stream>>>(blk_hist, total);
    bucket_base_kernel<<<1, 1, 0, stream>>>(total, base, row_start, NBK, N, E);
    bucket_off_kernel<<<NBK, 256, 0, stream>>>(blk_hist, base);
    bucket_scatter_kernel<<<NBLK_A, 256, 0, stream>>>(eidx, flag, blk_hist, ebuf, E, NBK, chunk);
    bucket_csr_kernel<<<NBK, 256, 0, stream>>>(ebuf, base, csr_src, row_start, N);

    unsigned xcblocks = (unsigned)((N * 16 + 255) / 256);
    xcast_kernel<<<xcblocks, 256, 0, stream>>>(x, xa, N);

    unsigned gth_blocks = (unsigned)((N * 64 + 511) / 512);
    gather_kernel<0><<<gth_blocks, 512, 0, stream>>>(row_start, csr_src, xa, xa, N);

    unsigned gblocks = (unsigned)(((N + 127) & ~127L) / 128);
    fused_gemm_kernel<<<gblocks, 512, 0, stream>>>(xa, W1l, W1r, b1, W2l, W2r, b2, gr, N);

    gather_kernel<1><<<gth_blocks, 512, 0, stream>>>(row_start, csr_src, gr, h2, N);

    unsigned pblocks = (unsigned)((P * 32 + 511) / 512);
    linkpred_kernel<<<pblocks, 512, 0, stream>>>(pairs, flag, h2, Wlp, blp, out, P);
}